// Round 10
// baseline (97.184 us; speedup 1.0000x reference)
//
#include <hip/hip_runtime.h>
#include <hip/hip_bf16.h>

// N=2048, D=768, H=12, Y=64. W = [Wq;Wk] as [1536][768].
#define NN 2048
#define DD 768
#define HH 12
#define HW 1536
#define SPLITS 8
#define KPW (NN/SPLITS)           // 256 k-rows per split
#define NCH (KPW/64)              // 4 chunks per split
#define LDP 72                    // 64 + 8 pad -> 2-way max on frag reads (free)

typedef __attribute__((ext_vector_type(8))) short bf16x8;
typedef __attribute__((ext_vector_type(4))) float f32x4;

// native v_exp_f32 / v_log_f32 (both base-2). __exp2f/__log2f collide with
// glibc math.h reserved identifiers under -x hip.
__device__ __forceinline__ float exp2g(float x) { return __builtin_amdgcn_exp2f(x); }
__device__ __forceinline__ float log2g(float x) { return __builtin_amdgcn_logf(x); }

// Fold beta*log2(e) = 0.125*1.4426950408889634 into Wq -> scores in base-2.
#define QSCALE 0.18033688011112042f

__device__ __forceinline__ short b16(float x) {
  __hip_bfloat16 h = __float2bfloat16(x);
  return *reinterpret_cast<short*>(&h);
}
__device__ __forceinline__ bf16x8 cvt8(float4 a, float4 b, float sc) {
  bf16x8 r;
  r[0] = b16(a.x * sc); r[1] = b16(a.y * sc);
  r[2] = b16(a.z * sc); r[3] = b16(a.w * sc);
  r[4] = b16(b.x * sc); r[5] = b16(b.y * sc);
  r[6] = b16(b.z * sc); r[7] = b16(b.w * sc);
  return r;
}

// ---------------- Kernel 1: fused convert + projection GEMM ------------------
// QK[2048][1536] = g[2048][768](fp32) * W[1536][768](fp32)^T, cast via bf16.
// W rows 0..767 = Wq (scaled by QSCALE), 768..1535 = Wk. Staging loads fp32
// directly (L3-cached), converts in-register during ds_write.
// 64x64 tile, BK=64, grid (32,24)=768 (3/CU), double-buffered, 1 barrier/kt.
__global__ __launch_bounds__(256) void proj_kernel(
    const float* __restrict__ g, const float* __restrict__ Wq,
    const float* __restrict__ Wk, __hip_bfloat16* __restrict__ QK,
    float* __restrict__ out) {
  __shared__ __align__(16) __hip_bfloat16 As[2][64 * LDP];
  __shared__ __align__(16) __hip_bfloat16 Bs[2][64 * LDP];
  const int t = threadIdx.x;
  const int wave = t >> 6, lane = t & 63;
  const int lr = lane & 15, lg = lane >> 4;
  const int wm = wave & 1, wn = wave >> 1;
  const int bm = blockIdx.x, bn = blockIdx.y;
  if (bm == 0 && bn == 0 && t == 0) out[0] = 0.0f;   // for reduce's atomicAdd

  const float* Wsrc = (bn < 12) ? (Wq + bn * 64 * DD) : (Wk + (bn - 12) * 64 * DD);
  const float sc = (bn < 12) ? QSCALE : 1.0f;

  const int r0 = t >> 3, s0c = (t & 7) * 8;
  const int r1 = r0 + 32;

  f32x4 acc[2][2] = {};

  // prologue: stage kt=0
  {
    const float* ga0 = g + (bm * 64 + r0) * DD + s0c;
    const float* ga1 = g + (bm * 64 + r1) * DD + s0c;
    const float* gb0 = Wsrc + r0 * DD + s0c;
    const float* gb1 = Wsrc + r1 * DD + s0c;
    *reinterpret_cast<bf16x8*>(&As[0][r0 * LDP + s0c]) =
        cvt8(*(const float4*)ga0, *(const float4*)(ga0 + 4), 1.0f);
    *reinterpret_cast<bf16x8*>(&As[0][r1 * LDP + s0c]) =
        cvt8(*(const float4*)ga1, *(const float4*)(ga1 + 4), 1.0f);
    *reinterpret_cast<bf16x8*>(&Bs[0][r0 * LDP + s0c]) =
        cvt8(*(const float4*)gb0, *(const float4*)(gb0 + 4), sc);
    *reinterpret_cast<bf16x8*>(&Bs[0][r1 * LDP + s0c]) =
        cvt8(*(const float4*)gb1, *(const float4*)(gb1 + 4), sc);
  }
  __syncthreads();

  for (int it = 0; it < 12; ++it) {
    const int cur = it & 1;
    float4 pa0, pa1, pa2, pa3, pb0, pb1, pb2, pb3;
    if (it < 11) {
      int kt = (it + 1) * 64;
      const float* ga0 = g + (bm * 64 + r0) * DD + kt + s0c;
      const float* ga1 = g + (bm * 64 + r1) * DD + kt + s0c;
      const float* gb0 = Wsrc + r0 * DD + kt + s0c;
      const float* gb1 = Wsrc + r1 * DD + kt + s0c;
      pa0 = *(const float4*)ga0; pa1 = *(const float4*)(ga0 + 4);
      pa2 = *(const float4*)ga1; pa3 = *(const float4*)(ga1 + 4);
      pb0 = *(const float4*)gb0; pb1 = *(const float4*)(gb0 + 4);
      pb2 = *(const float4*)gb1; pb3 = *(const float4*)(gb1 + 4);
    }
#pragma unroll
    for (int ks = 0; ks < 2; ++ks) {
      bf16x8 a[2], b[2];
#pragma unroll
      for (int mt = 0; mt < 2; ++mt)
        a[mt] = *reinterpret_cast<const bf16x8*>(&As[cur][(wm * 32 + mt * 16 + lr) * LDP + ks * 32 + lg * 8]);
#pragma unroll
      for (int nt = 0; nt < 2; ++nt)
        b[nt] = *reinterpret_cast<const bf16x8*>(&Bs[cur][(wn * 32 + nt * 16 + lr) * LDP + ks * 32 + lg * 8]);
#pragma unroll
      for (int mt = 0; mt < 2; ++mt)
#pragma unroll
        for (int nt = 0; nt < 2; ++nt)
          acc[mt][nt] = __builtin_amdgcn_mfma_f32_16x16x32_bf16(a[mt], b[nt], acc[mt][nt], 0, 0, 0);
    }
    if (it < 11) {
      const int nxt = cur ^ 1;
      *reinterpret_cast<bf16x8*>(&As[nxt][r0 * LDP + s0c]) = cvt8(pa0, pa1, 1.0f);
      *reinterpret_cast<bf16x8*>(&As[nxt][r1 * LDP + s0c]) = cvt8(pa2, pa3, 1.0f);
      *reinterpret_cast<bf16x8*>(&Bs[nxt][r0 * LDP + s0c]) = cvt8(pb0, pb1, sc);
      *reinterpret_cast<bf16x8*>(&Bs[nxt][r1 * LDP + s0c]) = cvt8(pb2, pb3, sc);
      __syncthreads();
    }
  }
#pragma unroll
  for (int mt = 0; mt < 2; ++mt) {
    int row = bm * 64 + wm * 32 + mt * 16 + lg * 4;
#pragma unroll
    for (int nt = 0; nt < 2; ++nt) {
      int col = bn * 64 + wn * 32 + nt * 16 + lr;
#pragma unroll
      for (int r = 0; r < 4; ++r)
        QK[(row + r) * HW + col] = __float2bfloat16(acc[mt][nt][r]);
    }
  }
}

// ---------------- Kernel 2: scores + per-lane online LSE, dbuf K -------------
// ROUND 10: occupancy push. grid (32 q-tiles of 64, 12 heads, 8 k-splits)
// = 3072 blocks -> 8 resident blocks/CU (LDS 18.4KB cap), 32 waves/CU
// (was 3 blocks / 12 waves). Wave w owns q rows q0+w*16..+15. Q frags
// loaded once direct from global; K staged in dbuf LDS, ONE barrier/chunk.
// Each lane keeps private (m,l) over its k-subset (k = kc+nt*16+lr).
__global__ __launch_bounds__(256) void attn_kernel(
    const __hip_bfloat16* __restrict__ QK, float2* __restrict__ part) {
  __shared__ __align__(16) __hip_bfloat16 Ks[2][64 * LDP];
  const int t = threadIdx.x;
  const int wave = t >> 6, lane = t & 63;
  const int lr = lane & 15, lg = lane >> 4;
  const int q0 = blockIdx.x * 64, h = blockIdx.y, sp = blockIdx.z;
  const int k0 = sp * KPW;
  const int r0 = t >> 3, s0 = (t & 7) * 8;
  const int r1 = r0 + 32;
  const int colK = DD + h * 64;

  // Q fragments: 2 direct loads, resident for the whole kernel
  bf16x8 aq[2];
#pragma unroll
  for (int z = 0; z < 2; ++z)
    aq[z] = *reinterpret_cast<const bf16x8*>(
        QK + (q0 + wave * 16 + lr) * HW + h * 64 + z * 32 + lg * 8);

  // prologue: stage chunk 0
  *reinterpret_cast<uint4*>(&Ks[0][r0 * LDP + s0]) =
      *reinterpret_cast<const uint4*>(QK + (k0 + r0) * HW + colK + s0);
  *reinterpret_cast<uint4*>(&Ks[0][r1 * LDP + s0]) =
      *reinterpret_cast<const uint4*>(QK + (k0 + r1) * HW + colK + s0);
  __syncthreads();

  float m[4], l[4];
#pragma unroll
  for (int r = 0; r < 4; ++r) { m[r] = -3.0e38f; l[r] = 0.0f; }

  for (int ci = 0; ci < NCH; ++ci) {
    const int cur = ci & 1;
    uint4 n0, n1;
    if (ci < NCH - 1) {
      int kc = k0 + (ci + 1) * 64;
      n0 = *reinterpret_cast<const uint4*>(QK + (kc + r0) * HW + colK + s0);
      n1 = *reinterpret_cast<const uint4*>(QK + (kc + r1) * HW + colK + s0);
    }
    f32x4 s[4] = {};
#pragma unroll
    for (int nt = 0; nt < 4; ++nt)
#pragma unroll
      for (int z = 0; z < 2; ++z) {
        bf16x8 b = *reinterpret_cast<const bf16x8*>(&Ks[cur][(nt * 16 + lr) * LDP + z * 32 + lg * 8]);
        s[nt] = __builtin_amdgcn_mfma_f32_16x16x32_bf16(aq[z], b, s[nt], 0, 0, 0);
      }
    // per-lane online update (scores already in base-2 units)
#pragma unroll
    for (int r = 0; r < 4; ++r) {
      float v0 = s[0][r], v1 = s[1][r], v2 = s[2][r], v3 = s[3][r];
      float cm = fmaxf(fmaxf(v0, v1), fmaxf(v2, v3));
      float mn = fmaxf(m[r], cm);
      float p = exp2g(v0 - mn) + exp2g(v1 - mn) +
                exp2g(v2 - mn) + exp2g(v3 - mn);
      l[r] = l[r] * exp2g(m[r] - mn) + p;
      m[r] = mn;
    }
    if (ci < NCH - 1) {
      *reinterpret_cast<uint4*>(&Ks[cur ^ 1][r0 * LDP + s0]) = n0;
      *reinterpret_cast<uint4*>(&Ks[cur ^ 1][r1 * LDP + s0]) = n1;
      __syncthreads();
    }
  }
  // butterfly merge across the 16 lr-lanes (lg bits untouched)
#pragma unroll
  for (int msk = 1; msk <= 8; msk <<= 1) {
#pragma unroll
    for (int r = 0; r < 4; ++r) {
      float mo = __shfl_xor(m[r], msk);
      float lo = __shfl_xor(l[r], msk);
      float mn = fmaxf(m[r], mo);
      l[r] = l[r] * exp2g(m[r] - mn) + lo * exp2g(mo - mn);
      m[r] = mn;
    }
  }
  if (lr == 0) {
#pragma unroll
    for (int r = 0; r < 4; ++r) {
      int q = q0 + wave * 16 + lg * 4 + r;
      part[(sp * HH + h) * NN + q] = make_float2(m[r], l[r]);
    }
  }
}

// ---------------- Kernel 3: merge 8 splits + global sum ----------------------
// 24 blocks x 1024 thr, one row each; out zeroed by proj_kernel.
__global__ __launch_bounds__(1024) void reduce_kernel(
    const float2* __restrict__ part, float* __restrict__ out) {
  const int t = threadIdx.x;
  const int row = blockIdx.x * 1024 + t;         // 0..24575 = (h*2048+q)
  float2 p[SPLITS];
#pragma unroll
  for (int sp = 0; sp < SPLITS; ++sp)
    p[sp] = part[sp * (HH * NN) + row];
  float mm = -3.0e38f;
#pragma unroll
  for (int sp = 0; sp < SPLITS; ++sp) mm = fmaxf(mm, p[sp].x);
  float ll = 0.0f;
#pragma unroll
  for (int sp = 0; sp < SPLITS; ++sp) ll += p[sp].y * exp2g(p[sp].x - mm);
  float lse = mm + log2g(ll);                    // base-2 lse
#pragma unroll
  for (int msk = 1; msk <= 32; msk <<= 1)
    lse += __shfl_xor(lse, msk);
  __shared__ float wsum[16];
  if ((t & 63) == 0) wsum[t >> 6] = lse;
  __syncthreads();
  if (t == 0) {
    float s = 0.0f;
#pragma unroll
    for (int i = 0; i < 16; ++i) s += wsum[i];
    atomicAdd(out, -5.545177444479562f * s);     // -(1/beta)*ln2 * sum(lse2)
  }
}

// ---------------- launch -----------------------------------------------------
extern "C" void kernel_launch(void* const* d_in, const int* in_sizes, int n_in,
                              void* d_out, int out_size, void* d_ws, size_t ws_size,
                              hipStream_t stream) {
  const float* g  = (const float*)d_in[0];
  const float* Wq = (const float*)d_in[1];
  const float* Wk = (const float*)d_in[2];
  float* out = (float*)d_out;

  char* ws = (char*)d_ws;
  __hip_bfloat16* QK = (__hip_bfloat16*)ws;              // [2048][1536] 6.3 MB
  float2* part = (float2*)(ws + 6291456);                // [8][12][2048] 1.57 MB

  proj_kernel<<<dim3(32, 24), 256, 0, stream>>>(g, Wq, Wk, QK, out);
  attn_kernel<<<dim3(32, HH, SPLITS), 256, 0, stream>>>(QK, part);
  reduce_kernel<<<24, 1024, 0, stream>>>(part, out);
}